// Round 4
// baseline (419.709 us; speedup 1.0000x reference)
//
#include <hip/hip_runtime.h>
#include <math.h>

#define BB 128
#define ID 512
#define NN 512
#define WDIM 32
#define RR 4
#define EPSF 1e-6f
#define NTILE 16   // k3 row tiles (32 rows each)

typedef float nt_float4 __attribute__((ext_vector_type(4)));

// ---- d_out layout (floats) ----
#define OFF_RV   ((size_t)0)
#define OFF_MEM  (OFF_RV + (size_t)BB*RR*WDIM)
#define OFF_LINK (OFF_MEM + (size_t)BB*NN*WDIM)
#define OFF_PREC (OFF_LINK + (size_t)BB*NN*NN)
#define OFF_RW   (OFF_PREC + (size_t)BB*NN)
#define OFF_WW   (OFF_RW + (size_t)BB*RR*NN)
#define OFF_USG  (OFF_WW + (size_t)BB*NN)

// ---- iface layout (per batch, stride 256 floats) ----
#define IF_RK 0
#define IF_RS 128
#define IF_WK 132
#define IF_WS 164
#define IF_EV 165
#define IF_WV 197
#define IF_FG 229
#define IF_AG 233
#define IF_WG 234
#define IF_RM 235

// ---- ws layout (floats) ----
#define WS_IFACE ((size_t)0)
#define WS_FW    (WS_IFACE + (size_t)BB*256)
#define WS_BW    (WS_FW + (size_t)BB*RR*NN)        // atomic-path bw accumulator
#define WS_PART  WS_BW                              // partial-path region (aliases bw)
#define WS_PART_FLOATS ((size_t)BB*NTILE*RR*NN)     // 16 MB: only if ws is big

__device__ __forceinline__ float sigm(float x) { return 1.0f / (1.0f + expf(-x)); }
__device__ __forceinline__ float softplusf(float x) { return fmaxf(x, 0.0f) + log1pf(expf(-fabsf(x))); }

struct HeadArgs {
  const float *Wrk, *brk, *Wrs, *brs, *Wwk, *bwk, *Wws, *bws, *Wev, *bev,
              *Wwv, *bwv, *Wfg, *bfg, *Wag, *bag, *Wwg, *bwg, *Wrm, *brm;
};

// ---------------- K1: linear heads + activations ----------------
__global__ __launch_bounds__(256) void k1_heads(const float* __restrict__ xi, HeadArgs ha,
                                                float* __restrict__ iface) {
  __shared__ __align__(16) float xs[ID];
  __shared__ float raw[256];
  int b = blockIdx.x, t = threadIdx.x;
  for (int i = t; i < ID; i += 256) xs[i] = xi[b * ID + i];
  __syncthreads();
  const float* Ws[10] = {ha.Wrk, ha.Wrs, ha.Wwk, ha.Wws, ha.Wev, ha.Wwv, ha.Wfg, ha.Wag, ha.Wwg, ha.Wrm};
  const float* bs[10] = {ha.brk, ha.brs, ha.bwk, ha.bws, ha.bev, ha.bwv, ha.bfg, ha.bag, ha.bwg, ha.brm};
  const int off[11] = {0, 128, 132, 164, 165, 197, 229, 233, 234, 235, 247};
  float val = 0.0f;
  int h = -1, row = 0;
  if (t < 247) {
    for (int k = 0; k < 10; ++k)
      if (t >= off[k] && t < off[k + 1]) { h = k; row = t - off[k]; }
    const float4* w4 = (const float4*)(Ws[h] + row * ID);
    const float4* x4 = (const float4*)xs;
    float acc = 0.0f;
    for (int i = 0; i < ID / 4; ++i) {
      float4 w = w4[i], x = x4[i];
      acc += w.x * x.x + w.y * x.y + w.z * x.z + w.w * x.w;
    }
    val = acc + bs[h][row];
  }
  raw[t] = val;
  __syncthreads();
  if (t < 247) {
    float o;
    if (h == 0 || h == 2 || h == 5) o = tanhf(val);
    else if (h == 1 || h == 3) o = softplusf(val);
    else if (h == 9) {
      int g = (t - 235) / 3;
      float a0 = raw[235 + g * 3], a1 = raw[236 + g * 3], a2 = raw[237 + g * 3];
      float mx = fmaxf(a0, fmaxf(a1, a2));
      o = expf(val - mx) / (expf(a0 - mx) + expf(a1 - mx) + expf(a2 - mx));
    } else o = sigm(val);
    iface[b * 256 + t] = o;
  }
}

// ---------------- K2: usage/alloc/write-addressing/memory-write ----------------
__global__ __launch_bounds__(512) void k2_write(const float* __restrict__ mem_in,
                                                const float* __restrict__ prec_in,
                                                const float* __restrict__ rw_in,
                                                const float* __restrict__ wwt_in,
                                                const float* __restrict__ usg_in,
                                                const float* __restrict__ iface,
                                                float* __restrict__ bw,
                                                float* __restrict__ out) {
  __shared__ __align__(16) float sif[256];
  __shared__ float sv[NN];
  __shared__ int si[NN];
  __shared__ float salloc[NN];
  __shared__ float sred[8];
  __shared__ float swt[8];
  int b = blockIdx.x, tid = threadIdx.x;
  int lane = tid & 63, wave = tid >> 6;

  // zero the bw accumulator for the atomic path (harmless in partial mode)
  for (int i = tid; i < RR * NN; i += 512) bw[(size_t)b * RR * NN + i] = 0.0f;

  if (tid < 256) sif[tid] = iface[b * 256 + tid];
  __syncthreads();

  // psi and usage update
  const float* rwb = rw_in + (size_t)b * RR * NN;
  float psi = 1.0f;
#pragma unroll
  for (int r = 0; r < RR; r++) psi *= 1.0f - sif[IF_FG + r] * rwb[r * NN + tid];
  float u = usg_in[b * NN + tid], wwt = wwt_in[b * NN + tid];
  u = (u + wwt - u * wwt) * psi;

  // ---- bitonic sort of (u, tid) ascending, in registers ----
  float v = u; int idx = tid;
  for (int k = 2; k <= NN; k <<= 1) {
    for (int j = k >> 1; j > 0; j >>= 1) {
      int p = tid ^ j;
      float pv; int pi;
      if (j >= 64) {
        sv[tid] = v; si[tid] = idx;
        __syncthreads();
        pv = sv[p]; pi = si[p];
        __syncthreads();
      } else {
        pv = __shfl_xor(v, j);
        pi = __shfl_xor(idx, j);
      }
      bool mineSmaller = (v < pv) || (v == pv && idx < pi);
      bool keepMin = (((tid & k) == 0) == (tid < p));
      bool take = keepMin ? !mineSmaller : mineSmaller;
      if (take) { v = pv; idx = pi; }
    }
  }

  // ---- exclusive product scan over sorted values ----
  float pr = v;
#pragma unroll
  for (int o = 1; o < 64; o <<= 1) {
    float q = __shfl_up(pr, o);
    if (lane >= o) pr *= q;
  }
  if (lane == 63) swt[wave] = pr;
  __syncthreads();
  float wp = 1.0f;
#pragma unroll
  for (int w = 0; w < 8; w++) if (w < wave) wp *= swt[w];
  float ep = __shfl_up(pr, 1);
  if (lane == 0) ep = 1.0f;
  float alloc_sorted = (1.0f - v) * (wp * ep);
  salloc[idx] = alloc_sorted;
  __syncthreads();
  float alloc = salloc[tid];

  // ---- write content addressing on OLD memory ----
  const float4* mrow = (const float4*)(mem_in + ((size_t)b * NN + tid) * WDIM);
  float4 mv[8];
  float dot = 0, nrm = 0, wkn = 0;
#pragma unroll
  for (int i = 0; i < 8; i++) {
    float4 m = mrow[i];
    mv[i] = m;
    const float4 kk = *(const float4*)&sif[IF_WK + 4 * i];
    dot += m.x * kk.x + m.y * kk.y + m.z * kk.z + m.w * kk.w;
    nrm += m.x * m.x + m.y * m.y + m.z * m.z + m.w * m.w;
    wkn += kk.x * kk.x + kk.y * kk.y + kk.z * kk.z + kk.w * kk.w;
  }
  float s = sif[IF_WS] * (dot / (sqrtf(nrm) * sqrtf(wkn) + EPSF));

  float m8 = s;
#pragma unroll
  for (int d = 32; d > 0; d >>= 1) m8 = fmaxf(m8, __shfl_down(m8, d));
  if (lane == 0) sred[wave] = m8;
  __syncthreads();
  float mx = sred[0];
#pragma unroll
  for (int w = 1; w < 8; w++) mx = fmaxf(mx, sred[w]);
  __syncthreads();
  float e = expf(s - mx);
  float sm = e;
#pragma unroll
  for (int d = 32; d > 0; d >>= 1) sm += __shfl_down(sm, d);
  if (lane == 0) sred[wave] = sm;
  __syncthreads();
  float esum = 0;
#pragma unroll
  for (int w = 0; w < 8; w++) esum += sred[w];
  __syncthreads();
  float wc = e / esum;

  float ww = sif[IF_WG] * (sif[IF_AG] * alloc + (1.0f - sif[IF_AG]) * wc);
  out[OFF_WW + b * NN + tid] = ww;
  out[OFF_USG + b * NN + tid] = u;

  float ws_ = ww;
#pragma unroll
  for (int d = 32; d > 0; d >>= 1) ws_ += __shfl_down(ws_, d);
  if (lane == 0) sred[wave] = ws_;
  __syncthreads();
  float wsum = 0;
#pragma unroll
  for (int w = 0; w < 8; w++) wsum += sred[w];
  out[OFF_PREC + b * NN + tid] = (1.0f - wsum) * prec_in[b * NN + tid] + ww;

  // memory erase + write
  float* mo = out + OFF_MEM + ((size_t)b * NN + tid) * WDIM;
#pragma unroll
  for (int i = 0; i < 8; i++) {
    float4 m = mv[i];
    float4 o;
    o.x = m.x * (1.0f - ww * sif[IF_EV + 4 * i + 0]) + ww * sif[IF_WV + 4 * i + 0];
    o.y = m.y * (1.0f - ww * sif[IF_EV + 4 * i + 1]) + ww * sif[IF_WV + 4 * i + 1];
    o.z = m.z * (1.0f - ww * sif[IF_EV + 4 * i + 2]) + ww * sif[IF_WV + 4 * i + 2];
    o.w = m.w * (1.0f - ww * sif[IF_EV + 4 * i + 3]) + ww * sif[IF_WV + 4 * i + 3];
    ((float4*)mo)[i] = o;
  }
}

// ---------------- K3: link update + fused fw/bw einsums ----------------
// Full-preload structure: 512 threads = 8 waves = 4 row-groups x 2 col-halves.
// Each wave preloads ALL 8 of its link rows (8 float4/lane) before the compute
// loop, so every global load is older than every store in the vmcnt queue —
// store completion (NT, acks at HBM) can never gate a load wait. 4x the
// per-wave MLP of the rolling-prefetch version, and half the column state.
template<int PARTIAL>
__global__ __launch_bounds__(512, 4) void k3_link(const float* __restrict__ link_in,
                                                  const float* __restrict__ prec_in,
                                                  const float* __restrict__ rw_in,
                                                  const float* __restrict__ ww_out,
                                                  float* __restrict__ link_out,
                                                  float* __restrict__ fw,
                                                  float* __restrict__ bw) {
  __shared__ __align__(16) float sww[NN];
  __shared__ __align__(16) float sprec[NN];
  __shared__ __align__(16) float srw[RR * NN];
  __shared__ float sbw[RR * NN];
  __shared__ float sfw[RR * 32];
  int b = blockIdx.y, tile = blockIdx.x, tid = threadIdx.x;
  int wave = tid >> 6, lane = tid & 63;
  int g = wave >> 1;      // row group 0..3 (8 rows each)
  int ch = wave & 1;      // column half 0..1 (256 cols each)
  int row0 = tile * 32 + g * 8;
  const size_t lbase = (size_t)b * NN * NN;
  const float* lbp = link_in + lbase;

  // ---- preissue ALL 8 link-row loads for this wave (before any store) ----
  float4 pl[8];
#pragma unroll
  for (int i = 0; i < 8; i++)
    pl[i] = ((const float4*)(lbp + (size_t)(row0 + i) * NN))[ch * 64 + lane];

  // ---- stage per-batch vectors to LDS (latency overlaps the pl loads) ----
  for (int i = tid; i < NN; i += 512) {
    sww[i] = ww_out[b * NN + i];
    sprec[i] = prec_in[b * NN + i];
  }
  for (int i = tid; i < RR * NN; i += 512) {
    srw[i] = rw_in[(size_t)b * RR * NN + i];
    sbw[i] = 0.0f;
  }
  if (tid < RR * 32) sfw[tid] = 0.0f;
  __syncthreads();

  // ---- column caches for this wave's half ----
  int c0 = ch * 256 + 4 * lane;
  float4 cww = ((const float4*)sww)[ch * 64 + lane];
  float4 cpr = ((const float4*)sprec)[ch * 64 + lane];
  float4 crw[RR];
#pragma unroll
  for (int r = 0; r < RR; r++) crw[r] = ((const float4*)(srw + r * NN))[ch * 64 + lane];

  float bwa[RR][4];
#pragma unroll
  for (int r = 0; r < RR; r++)
#pragma unroll
    for (int j = 0; j < 4; j++) bwa[r][j] = 0.0f;

  float wcc[4] = {cww.x, cww.y, cww.z, cww.w};
  float pcc[4] = {cpr.x, cpr.y, cpr.z, cpr.w};

  // ---- pure compute+store loop: no load waits anywhere in here ----
#pragma unroll
  for (int i = 0; i < 8; i++) {
    int row = row0 + i;
    float wwr = sww[row];
    float rwr[RR] = {srw[row], srw[NN + row], srw[2 * NN + row], srw[3 * NN + row]};
    float l[4] = {pl[i].x, pl[i].y, pl[i].z, pl[i].w};
    float fp[RR] = {0, 0, 0, 0};
#pragma unroll
    for (int j = 0; j < 4; j++) {
      float ln = (1.0f - wwr - wcc[j]) * l[j] + wwr * pcc[j];
      if (c0 + j == row) ln = 0.0f;
      l[j] = ln;
#pragma unroll
      for (int r = 0; r < RR; r++) bwa[r][j] += ln * rwr[r];
    }
#pragma unroll
    for (int r = 0; r < RR; r++) {
      float rc0 = (r == 0) ? crw[0].x : (r == 1) ? crw[1].x : (r == 2) ? crw[2].x : crw[3].x;
      float rc1 = (r == 0) ? crw[0].y : (r == 1) ? crw[1].y : (r == 2) ? crw[2].y : crw[3].y;
      float rc2 = (r == 0) ? crw[0].z : (r == 1) ? crw[1].z : (r == 2) ? crw[2].z : crw[3].z;
      float rc3 = (r == 0) ? crw[0].w : (r == 1) ? crw[1].w : (r == 2) ? crw[2].w : crw[3].w;
      fp[r] = l[0] * rc0 + l[1] * rc1 + l[2] * rc2 + l[3] * rc3;
    }
    nt_float4 ov = {l[0], l[1], l[2], l[3]};
    __builtin_nontemporal_store(ov, (nt_float4*)(link_out + lbase + (size_t)row * NN) + ch * 64 + lane);
    // reduce this row's fw partial (over this wave's 256 cols)
#pragma unroll
    for (int d = 32; d > 0; d >>= 1) {
      fp[0] += __shfl_down(fp[0], d);
      fp[1] += __shfl_down(fp[1], d);
      fp[2] += __shfl_down(fp[2], d);
      fp[3] += __shfl_down(fp[3], d);
    }
    if (lane == 0) {
      int rl = g * 8 + i;   // 0..31 within tile
      atomicAdd(&sfw[0 * 32 + rl], fp[0]);
      atomicAdd(&sfw[1 * 32 + rl], fp[1]);
      atomicAdd(&sfw[2 * 32 + rl], fp[2]);
      atomicAdd(&sfw[3 * 32 + rl], fp[3]);
    }
  }

  // ---- merge bw partials across waves via LDS atomics ----
#pragma unroll
  for (int r = 0; r < RR; r++)
#pragma unroll
    for (int j = 0; j < 4; j++) atomicAdd(&sbw[r * NN + c0 + j], bwa[r][j]);
  __syncthreads();

  // fw writeout (one coalesced store for the tile)
  if (tid < RR * 32) {
    int r = tid >> 5, j = tid & 31;
    fw[(size_t)b * RR * NN + r * NN + tile * 32 + j] = sfw[tid];
  }

  if (PARTIAL) {
    float* bp = bw + ((size_t)(b * NTILE + tile)) * RR * NN;
    for (int i = tid; i < RR * NN; i += 512) bp[i] = sbw[i];
  } else {
    float* bp = bw + (size_t)b * RR * NN;
    for (int i = tid; i < RR * NN; i += 512) atomicAdd(&bp[i], sbw[i]);
  }
}

// ---------------- K4: read addressing + read weights + read vectors ----------------
template<int PARTIAL>
__global__ __launch_bounds__(512) void k4_read(const float* __restrict__ iface,
                                               const float* __restrict__ fw,
                                               const float* __restrict__ bw,
                                               float* __restrict__ out) {
  __shared__ __align__(16) float srk[WDIM];
  __shared__ float sred[8];
  __shared__ float srwn[NN];
  __shared__ float spart[16][WDIM];
  int b = blockIdx.x >> 2, r = blockIdx.x & 3;
  int tid = threadIdx.x, lane = tid & 63, wave = tid >> 6;
  const float* ifb = iface + b * 256;
  if (tid < WDIM) srk[tid] = ifb[IF_RK + r * WDIM + tid];
  __syncthreads();
  float rkn2 = 0;
#pragma unroll
  for (int w = 0; w < WDIM; w++) { float v = srk[w]; rkn2 += v * v; }
  float rkn = sqrtf(rkn2);

  const float* mem = out + OFF_MEM + (size_t)b * NN * WDIM;
  const float4* mrow = (const float4*)(mem + (size_t)tid * WDIM);
  float d = 0, nrm = 0;
#pragma unroll
  for (int i = 0; i < 8; i++) {
    float4 m = mrow[i];
    const float4 kk = *(const float4*)&srk[4 * i];
    nrm += m.x * m.x + m.y * m.y + m.z * m.z + m.w * m.w;
    d += m.x * kk.x + m.y * kk.y + m.z * kk.z + m.w * kk.w;
  }
  float s = ifb[IF_RS + r] * (d / (sqrtf(nrm) * rkn + EPSF));

  float m8 = s;
#pragma unroll
  for (int dd = 32; dd > 0; dd >>= 1) m8 = fmaxf(m8, __shfl_down(m8, dd));
  if (lane == 0) sred[wave] = m8;
  __syncthreads();
  float mx = sred[0];
#pragma unroll
  for (int w = 1; w < 8; w++) mx = fmaxf(mx, sred[w]);
  __syncthreads();
  float e = expf(s - mx);
  float sm = e;
#pragma unroll
  for (int dd = 32; dd > 0; dd >>= 1) sm += __shfl_down(sm, dd);
  if (lane == 0) sred[wave] = sm;
  __syncthreads();
  float esum = 0;
#pragma unroll
  for (int w = 0; w < 8; w++) esum += sred[w];
  float rc = e / esum;

  float bwv;
  if (PARTIAL) {
    const float* pp = bw + ((size_t)b * NTILE * RR + r) * NN + tid;
    float acc = 0.0f;
#pragma unroll
    for (int t = 0; t < NTILE; t++) acc += pp[(size_t)t * RR * NN];
    bwv = acc;
  } else {
    bwv = bw[((size_t)b * RR + r) * NN + tid];
  }
  float fwv = fw[((size_t)b * RR + r) * NN + tid];
  float m0 = ifb[IF_RM + 3 * r], m1 = ifb[IF_RM + 3 * r + 1], m2 = ifb[IF_RM + 3 * r + 2];
  float v = m0 * bwv + m1 * rc + m2 * fwv;
  srwn[tid] = v;
  out[OFF_RW + ((size_t)b * RR + r) * NN + tid] = v;
  __syncthreads();

  // rv[b,r,w] = sum_n srwn[n] * mem[n][w]
  int w = tid & 31, part = tid >> 5;     // 16 partitions of 32 rows
  float acc = 0;
  const float* mp = mem + (size_t)part * 32 * WDIM + w;
  const float* rp = srwn + part * 32;
#pragma unroll
  for (int n = 0; n < 32; n++) acc += rp[n] * mp[(size_t)n * WDIM];
  spart[part][w] = acc;
  __syncthreads();
  if (tid < WDIM) {
    float vv = 0;
#pragma unroll
    for (int p = 0; p < 16; p++) vv += spart[p][tid];
    out[OFF_RV + ((size_t)b * RR + r) * WDIM + tid] = vv;
  }
}

extern "C" void kernel_launch(void* const* d_in, const int* in_sizes, int n_in,
                              void* d_out, int out_size, void* d_ws, size_t ws_size,
                              hipStream_t stream) {
  const float* xi = (const float*)d_in[0];
  const float* mem = (const float*)d_in[1];
  const float* link = (const float*)d_in[2];
  const float* prec = (const float*)d_in[3];
  const float* rw = (const float*)d_in[4];
  const float* wwt = (const float*)d_in[5];
  const float* usg = (const float*)d_in[6];
  HeadArgs ha;
  ha.Wrk = (const float*)d_in[7];  ha.brk = (const float*)d_in[8];
  ha.Wrs = (const float*)d_in[9];  ha.brs = (const float*)d_in[10];
  ha.Wwk = (const float*)d_in[11]; ha.bwk = (const float*)d_in[12];
  ha.Wws = (const float*)d_in[13]; ha.bws = (const float*)d_in[14];
  ha.Wev = (const float*)d_in[15]; ha.bev = (const float*)d_in[16];
  ha.Wwv = (const float*)d_in[17]; ha.bwv = (const float*)d_in[18];
  ha.Wfg = (const float*)d_in[19]; ha.bfg = (const float*)d_in[20];
  ha.Wag = (const float*)d_in[21]; ha.bag = (const float*)d_in[22];
  ha.Wwg = (const float*)d_in[23]; ha.bwg = (const float*)d_in[24];
  ha.Wrm = (const float*)d_in[25]; ha.brm = (const float*)d_in[26];

  float* out = (float*)d_out;
  float* ws = (float*)d_ws;
  float* iface = ws + WS_IFACE;
  float* fwbuf = ws + WS_FW;
  float* bwbuf = ws + WS_BW;

  const size_t need_part_bytes = (WS_PART + WS_PART_FLOATS) * sizeof(float);
  const bool use_partial = ws_size >= need_part_bytes;

  k1_heads<<<BB, 256, 0, stream>>>(xi, ha, iface);
  k2_write<<<BB, 512, 0, stream>>>(mem, prec, rw, wwt, usg, iface, bwbuf, out);
  if (use_partial) {
    k3_link<1><<<dim3(NTILE, BB), 512, 0, stream>>>(link, prec, rw, out + OFF_WW, out + OFF_LINK, fwbuf, ws + WS_PART);
    k4_read<1><<<BB * RR, 512, 0, stream>>>(iface, fwbuf, ws + WS_PART, out);
  } else {
    k3_link<0><<<dim3(NTILE, BB), 512, 0, stream>>>(link, prec, rw, out + OFF_WW, out + OFF_LINK, fwbuf, bwbuf);
    k4_read<0><<<BB * RR, 512, 0, stream>>>(iface, fwbuf, bwbuf, out);
  }
}

// Round 5
// 375.661 us; speedup vs baseline: 1.1173x; 1.1173x over previous
//
#include <hip/hip_runtime.h>
#include <math.h>

#define BB 128
#define ID 512
#define NN 512
#define WDIM 32
#define RR 4
#define EPSF 1e-6f
#define NTILE 16   // k3 row tiles (32 rows each)

typedef float nt_float4 __attribute__((ext_vector_type(4)));

// ---- d_out layout (floats) ----
#define OFF_RV   ((size_t)0)
#define OFF_MEM  (OFF_RV + (size_t)BB*RR*WDIM)
#define OFF_LINK (OFF_MEM + (size_t)BB*NN*WDIM)
#define OFF_PREC (OFF_LINK + (size_t)BB*NN*NN)
#define OFF_RW   (OFF_PREC + (size_t)BB*NN)
#define OFF_WW   (OFF_RW + (size_t)BB*RR*NN)
#define OFF_USG  (OFF_WW + (size_t)BB*NN)

// ---- iface layout (per batch, stride 256 floats) ----
#define IF_RK 0
#define IF_RS 128
#define IF_WK 132
#define IF_WS 164
#define IF_EV 165
#define IF_WV 197
#define IF_FG 229
#define IF_AG 233
#define IF_WG 234
#define IF_RM 235

// ---- ws layout (floats) ----
#define WS_IFACE ((size_t)0)
#define WS_FW    (WS_IFACE + (size_t)BB*256)
#define WS_BW    (WS_FW + (size_t)BB*RR*NN)        // atomic-path bw accumulator
#define WS_PART  WS_BW                              // partial-path region (aliases bw)
#define WS_PART_FLOATS ((size_t)BB*NTILE*RR*NN)     // 16 MB: only if ws is big

__device__ __forceinline__ float sigm(float x) { return 1.0f / (1.0f + expf(-x)); }
__device__ __forceinline__ float softplusf(float x) { return fmaxf(x, 0.0f) + log1pf(expf(-fabsf(x))); }

struct HeadArgs {
  const float *Wrk, *brk, *Wrs, *brs, *Wwk, *bwk, *Wws, *bws, *Wev, *bev,
              *Wwv, *bwv, *Wfg, *bfg, *Wag, *bag, *Wwg, *bwg, *Wrm, *brm;
};

// ---------------- K1: linear heads + activations ----------------
__global__ __launch_bounds__(256) void k1_heads(const float* __restrict__ xi, HeadArgs ha,
                                                float* __restrict__ iface) {
  __shared__ __align__(16) float xs[ID];
  __shared__ float raw[256];
  int b = blockIdx.x, t = threadIdx.x;
  for (int i = t; i < ID; i += 256) xs[i] = xi[b * ID + i];
  __syncthreads();
  const float* Ws[10] = {ha.Wrk, ha.Wrs, ha.Wwk, ha.Wws, ha.Wev, ha.Wwv, ha.Wfg, ha.Wag, ha.Wwg, ha.Wrm};
  const float* bs[10] = {ha.brk, ha.brs, ha.bwk, ha.bws, ha.bev, ha.bwv, ha.bfg, ha.bag, ha.bwg, ha.brm};
  const int off[11] = {0, 128, 132, 164, 165, 197, 229, 233, 234, 235, 247};
  float val = 0.0f;
  int h = -1, row = 0;
  if (t < 247) {
    for (int k = 0; k < 10; ++k)
      if (t >= off[k] && t < off[k + 1]) { h = k; row = t - off[k]; }
    const float4* w4 = (const float4*)(Ws[h] + row * ID);
    const float4* x4 = (const float4*)xs;
    float acc = 0.0f;
    for (int i = 0; i < ID / 4; ++i) {
      float4 w = w4[i], x = x4[i];
      acc += w.x * x.x + w.y * x.y + w.z * x.z + w.w * x.w;
    }
    val = acc + bs[h][row];
  }
  raw[t] = val;
  __syncthreads();
  if (t < 247) {
    float o;
    if (h == 0 || h == 2 || h == 5) o = tanhf(val);
    else if (h == 1 || h == 3) o = softplusf(val);
    else if (h == 9) {
      int g = (t - 235) / 3;
      float a0 = raw[235 + g * 3], a1 = raw[236 + g * 3], a2 = raw[237 + g * 3];
      float mx = fmaxf(a0, fmaxf(a1, a2));
      o = expf(val - mx) / (expf(a0 - mx) + expf(a1 - mx) + expf(a2 - mx));
    } else o = sigm(val);
    iface[b * 256 + t] = o;
  }
}

// ---------------- K2: usage/alloc/write-addressing/memory-write ----------------
// Sort-free allocation: alloc[i] = (1-u[i]) * prod over {j: (u[j],j) <lex (u[i],i)} u[j].
// Same multiplicand set as the reference's sorted cumprod, computed directly per
// thread from LDS (broadcast reads) — removes 45 bitonic stages + 24 barriers.
__global__ __launch_bounds__(512) void k2_write(const float* __restrict__ mem_in,
                                                const float* __restrict__ prec_in,
                                                const float* __restrict__ rw_in,
                                                const float* __restrict__ wwt_in,
                                                const float* __restrict__ usg_in,
                                                const float* __restrict__ iface,
                                                float* __restrict__ bw,
                                                float* __restrict__ out) {
  __shared__ __align__(16) float sif[256];
  __shared__ __align__(16) float su[NN];
  __shared__ float sred[8];
  int b = blockIdx.x, tid = threadIdx.x;
  int lane = tid & 63, wave = tid >> 6;

  // zero the bw accumulator for the atomic path (harmless in partial mode)
  for (int i = tid; i < RR * NN; i += 512) bw[(size_t)b * RR * NN + i] = 0.0f;

  if (tid < 256) sif[tid] = iface[b * 256 + tid];
  __syncthreads();

  // psi and usage update
  const float* rwb = rw_in + (size_t)b * RR * NN;
  float psi = 1.0f;
#pragma unroll
  for (int r = 0; r < RR; r++) psi *= 1.0f - sif[IF_FG + r] * rwb[r * NN + tid];
  float u = usg_in[b * NN + tid], wwt = wwt_in[b * NN + tid];
  u = (u + wwt - u * wwt) * psi;

  su[tid] = u;
  __syncthreads();

  // direct conditional product (lex order (u[j], j) < (u[tid], tid))
  float pr = 1.0f;
#pragma unroll 4
  for (int j = 0; j < NN; j += 4) {
    float4 uu = *(const float4*)&su[j];
    pr *= ((uu.x < u) || (uu.x == u && (j + 0) < tid)) ? uu.x : 1.0f;
    pr *= ((uu.y < u) || (uu.y == u && (j + 1) < tid)) ? uu.y : 1.0f;
    pr *= ((uu.z < u) || (uu.z == u && (j + 2) < tid)) ? uu.z : 1.0f;
    pr *= ((uu.w < u) || (uu.w == u && (j + 3) < tid)) ? uu.w : 1.0f;
  }
  float alloc = (1.0f - u) * pr;

  // ---- write content addressing on OLD memory ----
  const float4* mrow = (const float4*)(mem_in + ((size_t)b * NN + tid) * WDIM);
  float4 mv[8];
  float dot = 0, nrm = 0, wkn = 0;
#pragma unroll
  for (int i = 0; i < 8; i++) {
    float4 m = mrow[i];
    mv[i] = m;
    const float4 kk = *(const float4*)&sif[IF_WK + 4 * i];
    dot += m.x * kk.x + m.y * kk.y + m.z * kk.z + m.w * kk.w;
    nrm += m.x * m.x + m.y * m.y + m.z * m.z + m.w * m.w;
    wkn += kk.x * kk.x + kk.y * kk.y + kk.z * kk.z + kk.w * kk.w;
  }
  float s = sif[IF_WS] * (dot / (sqrtf(nrm) * sqrtf(wkn) + EPSF));

  float m8 = s;
#pragma unroll
  for (int d = 32; d > 0; d >>= 1) m8 = fmaxf(m8, __shfl_down(m8, d));
  if (lane == 0) sred[wave] = m8;
  __syncthreads();
  float mx = sred[0];
#pragma unroll
  for (int w = 1; w < 8; w++) mx = fmaxf(mx, sred[w]);
  __syncthreads();
  float e = expf(s - mx);
  float sm = e;
#pragma unroll
  for (int d = 32; d > 0; d >>= 1) sm += __shfl_down(sm, d);
  if (lane == 0) sred[wave] = sm;
  __syncthreads();
  float esum = 0;
#pragma unroll
  for (int w = 0; w < 8; w++) esum += sred[w];
  __syncthreads();
  float wc = e / esum;

  float ww = sif[IF_WG] * (sif[IF_AG] * alloc + (1.0f - sif[IF_AG]) * wc);
  out[OFF_WW + b * NN + tid] = ww;
  out[OFF_USG + b * NN + tid] = u;

  float ws_ = ww;
#pragma unroll
  for (int d = 32; d > 0; d >>= 1) ws_ += __shfl_down(ws_, d);
  if (lane == 0) sred[wave] = ws_;
  __syncthreads();
  float wsum = 0;
#pragma unroll
  for (int w = 0; w < 8; w++) wsum += sred[w];
  out[OFF_PREC + b * NN + tid] = (1.0f - wsum) * prec_in[b * NN + tid] + ww;

  // memory erase + write
  float* mo = out + OFF_MEM + ((size_t)b * NN + tid) * WDIM;
#pragma unroll
  for (int i = 0; i < 8; i++) {
    float4 m = mv[i];
    float4 o;
    o.x = m.x * (1.0f - ww * sif[IF_EV + 4 * i + 0]) + ww * sif[IF_WV + 4 * i + 0];
    o.y = m.y * (1.0f - ww * sif[IF_EV + 4 * i + 1]) + ww * sif[IF_WV + 4 * i + 1];
    o.z = m.z * (1.0f - ww * sif[IF_EV + 4 * i + 2]) + ww * sif[IF_WV + 4 * i + 2];
    o.w = m.w * (1.0f - ww * sif[IF_EV + 4 * i + 3]) + ww * sif[IF_WV + 4 * i + 3];
    ((float4*)mo)[i] = o;
  }
}

// ---------------- K3: link update + fused fw/bw einsums (R0 structure) ----------------
template<int PARTIAL>
__global__ __launch_bounds__(256) void k3_link(const float* __restrict__ link_in,
                                               const float* __restrict__ prec_in,
                                               const float* __restrict__ rw_in,
                                               const float* __restrict__ ww_out,
                                               float* __restrict__ link_out,
                                               float* __restrict__ fw,
                                               float* __restrict__ bw) {
  __shared__ __align__(16) float sww[NN];
  __shared__ __align__(16) float sprec[NN];
  __shared__ __align__(16) float srw[RR * NN];
  __shared__ float sbw[RR * NN];
  int b = blockIdx.y, tile = blockIdx.x, tid = threadIdx.x;
  for (int i = tid; i < NN; i += 256) {
    sww[i] = ww_out[b * NN + i];
    sprec[i] = prec_in[b * NN + i];
  }
  for (int i = tid; i < RR * NN; i += 256) {
    srw[i] = rw_in[(size_t)b * RR * NN + i];
    sbw[i] = 0.0f;
  }
  __syncthreads();

  int wave = tid >> 6, lane = tid & 63;
  float4 cww[2], cpr[2], crw[RR][2];
#pragma unroll
  for (int h = 0; h < 2; h++) {
    cww[h] = ((const float4*)sww)[h * 64 + lane];
    cpr[h] = ((const float4*)sprec)[h * 64 + lane];
#pragma unroll
    for (int r = 0; r < RR; r++) crw[r][h] = ((const float4*)(srw + r * NN))[h * 64 + lane];
  }

  float bwa[RR][8];
#pragma unroll
  for (int r = 0; r < RR; r++)
#pragma unroll
    for (int j = 0; j < 8; j++) bwa[r][j] = 0.0f;

  const size_t lbase = (size_t)b * NN * NN;
  const float* lbp = link_in + lbase;
  int row0 = tile * 32 + wave;

  float4 nv0 = ((const float4*)(lbp + (size_t)row0 * NN))[lane];
  float4 nv1 = ((const float4*)(lbp + (size_t)row0 * NN))[64 + lane];

  for (int i = 0; i < 8; i++) {
    int row = row0 + 4 * i;
    float4 cv[2] = {nv0, nv1};
    if (i < 7) {
      const float4* Ln = (const float4*)(lbp + (size_t)(row + 4) * NN);
      nv0 = Ln[lane];
      nv1 = Ln[64 + lane];
    }
    float wwr = sww[row];
    float rwr[RR] = {srw[row], srw[NN + row], srw[2 * NN + row], srw[3 * NN + row]};
    nt_float4* Lo = (nt_float4*)(link_out + lbase + (size_t)row * NN);
    float fp[RR] = {0, 0, 0, 0};
#pragma unroll
    for (int h = 0; h < 2; h++) {
      float4 lv = cv[h];
      float l[4] = {lv.x, lv.y, lv.z, lv.w};
      float wc[4] = {cww[h].x, cww[h].y, cww[h].z, cww[h].w};
      float pc[4] = {cpr[h].x, cpr[h].y, cpr[h].z, cpr[h].w};
      int c0 = h * 256 + 4 * lane;
#pragma unroll
      for (int j = 0; j < 4; j++) {
        float ln = (1.0f - wwr - wc[j]) * l[j] + wwr * pc[j];
        if (c0 + j == row) ln = 0.0f;
        l[j] = ln;
#pragma unroll
        for (int r = 0; r < RR; r++) bwa[r][h * 4 + j] += ln * rwr[r];
      }
#pragma unroll
      for (int r = 0; r < RR; r++) {
        float rc0 = (r == 0) ? crw[0][h].x : (r == 1) ? crw[1][h].x : (r == 2) ? crw[2][h].x : crw[3][h].x;
        float rc1 = (r == 0) ? crw[0][h].y : (r == 1) ? crw[1][h].y : (r == 2) ? crw[2][h].y : crw[3][h].y;
        float rc2 = (r == 0) ? crw[0][h].z : (r == 1) ? crw[1][h].z : (r == 2) ? crw[2][h].z : crw[3][h].z;
        float rc3 = (r == 0) ? crw[0][h].w : (r == 1) ? crw[1][h].w : (r == 2) ? crw[2][h].w : crw[3][h].w;
        fp[r] += l[0] * rc0 + l[1] * rc1 + l[2] * rc2 + l[3] * rc3;
      }
      nt_float4 ov = {l[0], l[1], l[2], l[3]};
      __builtin_nontemporal_store(ov, &Lo[h * 64 + lane]);   // link_out is never re-read: bypass caches
    }
#pragma unroll
    for (int d = 32; d > 0; d >>= 1) {
      fp[0] += __shfl_down(fp[0], d);
      fp[1] += __shfl_down(fp[1], d);
      fp[2] += __shfl_down(fp[2], d);
      fp[3] += __shfl_down(fp[3], d);
    }
    if (lane == 0) {
      float* fwb = fw + (size_t)b * RR * NN;
      fwb[0 * NN + row] = fp[0];
      fwb[1 * NN + row] = fp[1];
      fwb[2 * NN + row] = fp[2];
      fwb[3 * NN + row] = fp[3];
    }
  }

  // combine bw register partials across the 4 waves via LDS, then global merge
  for (int w = 0; w < 4; w++) {
    if (wave == w) {
#pragma unroll
      for (int r = 0; r < RR; r++)
#pragma unroll
        for (int h = 0; h < 2; h++)
#pragma unroll
          for (int j = 0; j < 4; j++)
            sbw[r * NN + h * 256 + 4 * lane + j] += bwa[r][h * 4 + j];
    }
    __syncthreads();
  }
  if (PARTIAL) {
    float* bp = bw + ((size_t)(b * NTILE + tile)) * RR * NN;
    for (int i = tid; i < RR * NN; i += 256) bp[i] = sbw[i];
  } else {
    float* bp = bw + (size_t)b * RR * NN;
    for (int i = tid; i < RR * NN; i += 256) atomicAdd(&bp[i], sbw[i]);
  }
}

// ---------------- K4: read addressing + read weights + read vectors ----------------
// Merged heads: one block per batch (grid BB, 512 thr); mem read once for all 4 r.
template<int PARTIAL>
__global__ __launch_bounds__(512) void k4_read(const float* __restrict__ iface,
                                               const float* __restrict__ fw,
                                               const float* __restrict__ bw,
                                               float* __restrict__ out) {
  __shared__ __align__(16) float srk[RR][WDIM];
  __shared__ float smax[8][RR];
  __shared__ float ssum[8][RR];
  __shared__ __align__(16) float srwn[RR][NN];
  __shared__ float spart[RR][16][WDIM];
  int b = blockIdx.x;
  int tid = threadIdx.x, lane = tid & 63, wave = tid >> 6;
  const float* ifb = iface + b * 256;
  if (tid < RR * WDIM) srk[tid >> 5][tid & 31] = ifb[IF_RK + tid];
  __syncthreads();

  float rkn[RR];
#pragma unroll
  for (int r = 0; r < RR; r++) {
    float a = 0;
#pragma unroll
    for (int w = 0; w < WDIM; w++) { float t = srk[r][w]; a += t * t; }
    rkn[r] = sqrtf(a);
  }

  const float* mem = out + OFF_MEM + (size_t)b * NN * WDIM;
  const float4* mrow = (const float4*)(mem + (size_t)tid * WDIM);
  float d[RR] = {0, 0, 0, 0};
  float nrm = 0;
#pragma unroll
  for (int i = 0; i < 8; i++) {
    float4 m = mrow[i];
    nrm += m.x * m.x + m.y * m.y + m.z * m.z + m.w * m.w;
#pragma unroll
    for (int r = 0; r < RR; r++) {
      const float4 kk = *(const float4*)&srk[r][4 * i];
      d[r] += m.x * kk.x + m.y * kk.y + m.z * kk.z + m.w * kk.w;
    }
  }
  float sq = sqrtf(nrm);
  float s[RR];
#pragma unroll
  for (int r = 0; r < RR; r++) s[r] = ifb[IF_RS + r] * (d[r] / (sq * rkn[r] + EPSF));

  float m8[RR] = {s[0], s[1], s[2], s[3]};
#pragma unroll
  for (int dd = 32; dd > 0; dd >>= 1)
#pragma unroll
    for (int r = 0; r < RR; r++) m8[r] = fmaxf(m8[r], __shfl_down(m8[r], dd));
  if (lane == 0)
#pragma unroll
    for (int r = 0; r < RR; r++) smax[wave][r] = m8[r];
  __syncthreads();
  float e[RR], sm[RR];
#pragma unroll
  for (int r = 0; r < RR; r++) {
    float mx = smax[0][r];
#pragma unroll
    for (int w = 1; w < 8; w++) mx = fmaxf(mx, smax[w][r]);
    e[r] = expf(s[r] - mx);
    sm[r] = e[r];
  }
#pragma unroll
  for (int dd = 32; dd > 0; dd >>= 1)
#pragma unroll
    for (int r = 0; r < RR; r++) sm[r] += __shfl_down(sm[r], dd);
  if (lane == 0)
#pragma unroll
    for (int r = 0; r < RR; r++) ssum[wave][r] = sm[r];
  __syncthreads();

  float v[RR];
#pragma unroll
  for (int r = 0; r < RR; r++) {
    float esum = 0;
#pragma unroll
    for (int w = 0; w < 8; w++) esum += ssum[w][r];
    float rc = e[r] / esum;

    float bwv;
    if (PARTIAL) {
      float acc = 0.0f;
#pragma unroll
      for (int t = 0; t < NTILE; t++)
        acc += bw[((size_t)(b * NTILE + t)) * RR * NN + r * NN + tid];
      bwv = acc;
    } else {
      bwv = bw[((size_t)b * RR + r) * NN + tid];
    }
    float fwv = fw[((size_t)b * RR + r) * NN + tid];
    float m0 = ifb[IF_RM + 3 * r], m1 = ifb[IF_RM + 3 * r + 1], m2 = ifb[IF_RM + 3 * r + 2];
    v[r] = m0 * bwv + m1 * rc + m2 * fwv;
    srwn[r][tid] = v[r];
    out[OFF_RW + ((size_t)b * RR + r) * NN + tid] = v[r];
  }
  __syncthreads();

  // rv[b,r,w] = sum_n srwn[r][n] * mem[n][w] — 16 partitions of 32 rows
  int w = tid & 31, part = tid >> 5;
  float acc[RR] = {0, 0, 0, 0};
  const float* mp = mem + (size_t)part * 32 * WDIM + w;
  const float* rp0 = &srwn[0][part * 32];
#pragma unroll
  for (int n = 0; n < 32; n++) {
    float mvv = mp[(size_t)n * WDIM];
#pragma unroll
    for (int r = 0; r < RR; r++) acc[r] += srwn[r][part * 32 + n] * mvv;
  }
#pragma unroll
  for (int r = 0; r < RR; r++) spart[r][part][w] = acc[r];
  __syncthreads();
  if (tid < RR * WDIM) {
    int r = tid >> 5, w2 = tid & 31;
    float vv = 0;
#pragma unroll
    for (int p = 0; p < 16; p++) vv += spart[r][p][w2];
    out[OFF_RV + ((size_t)b * RR + r) * WDIM + w2] = vv;
  }
}

extern "C" void kernel_launch(void* const* d_in, const int* in_sizes, int n_in,
                              void* d_out, int out_size, void* d_ws, size_t ws_size,
                              hipStream_t stream) {
  const float* xi = (const float*)d_in[0];
  const float* mem = (const float*)d_in[1];
  const float* link = (const float*)d_in[2];
  const float* prec = (const float*)d_in[3];
  const float* rw = (const float*)d_in[4];
  const float* wwt = (const float*)d_in[5];
  const float* usg = (const float*)d_in[6];
  HeadArgs ha;
  ha.Wrk = (const float*)d_in[7];  ha.brk = (const float*)d_in[8];
  ha.Wrs = (const float*)d_in[9];  ha.brs = (const float*)d_in[10];
  ha.Wwk = (const float*)d_in[11]; ha.bwk = (const float*)d_in[12];
  ha.Wws = (const float*)d_in[13]; ha.bws = (const float*)d_in[14];
  ha.Wev = (const float*)d_in[15]; ha.bev = (const float*)d_in[16];
  ha.Wwv = (const float*)d_in[17]; ha.bwv = (const float*)d_in[18];
  ha.Wfg = (const float*)d_in[19]; ha.bfg = (const float*)d_in[20];
  ha.Wag = (const float*)d_in[21]; ha.bag = (const float*)d_in[22];
  ha.Wwg = (const float*)d_in[23]; ha.bwg = (const float*)d_in[24];
  ha.Wrm = (const float*)d_in[25]; ha.brm = (const float*)d_in[26];

  float* out = (float*)d_out;
  float* ws = (float*)d_ws;
  float* iface = ws + WS_IFACE;
  float* fwbuf = ws + WS_FW;
  float* bwbuf = ws + WS_BW;

  const size_t need_part_bytes = (WS_PART + WS_PART_FLOATS) * sizeof(float);
  const bool use_partial = ws_size >= need_part_bytes;

  k1_heads<<<BB, 256, 0, stream>>>(xi, ha, iface);
  k2_write<<<BB, 512, 0, stream>>>(mem, prec, rw, wwt, usg, iface, bwbuf, out);
  if (use_partial) {
    k3_link<1><<<dim3(NTILE, BB), 256, 0, stream>>>(link, prec, rw, out + OFF_WW, out + OFF_LINK, fwbuf, ws + WS_PART);
    k4_read<1><<<BB, 512, 0, stream>>>(iface, fwbuf, ws + WS_PART, out);
  } else {
    k3_link<0><<<dim3(NTILE, BB), 256, 0, stream>>>(link, prec, rw, out + OFF_WW, out + OFF_LINK, fwbuf, bwbuf);
    k4_read<0><<<BB, 512, 0, stream>>>(iface, fwbuf, bwbuf, out);
  }
}

// Round 6
// 351.131 us; speedup vs baseline: 1.1953x; 1.0699x over previous
//
#include <hip/hip_runtime.h>
#include <math.h>

#define BB 128
#define ID 512
#define NN 512
#define WDIM 32
#define RR 4
#define EPSF 1e-6f
#define NTILE 16   // k3 row tiles (32 rows each)

typedef float nt_float4 __attribute__((ext_vector_type(4)));

// ---- d_out layout (floats) ----
#define OFF_RV   ((size_t)0)
#define OFF_MEM  (OFF_RV + (size_t)BB*RR*WDIM)
#define OFF_LINK (OFF_MEM + (size_t)BB*NN*WDIM)
#define OFF_PREC (OFF_LINK + (size_t)BB*NN*NN)
#define OFF_RW   (OFF_PREC + (size_t)BB*NN)
#define OFF_WW   (OFF_RW + (size_t)BB*RR*NN)
#define OFF_USG  (OFF_WW + (size_t)BB*NN)

// ---- iface layout (per batch, stride 256 floats) ----
#define IF_RK 0
#define IF_RS 128
#define IF_WK 132
#define IF_WS 164
#define IF_EV 165
#define IF_WV 197
#define IF_FG 229
#define IF_AG 233
#define IF_WG 234
#define IF_RM 235

// ---- ws layout (floats) ----
#define WS_IFACE ((size_t)0)
#define WS_FW    (WS_IFACE + (size_t)BB*256)
#define WS_BW    (WS_FW + (size_t)BB*RR*NN)        // atomic-path bw accumulator
#define WS_PART  WS_BW                              // partial-path region (aliases bw)
#define WS_PART_FLOATS ((size_t)BB*NTILE*RR*NN)     // 16 MB: only if ws is big

__device__ __forceinline__ float sigm(float x) { return 1.0f / (1.0f + expf(-x)); }
__device__ __forceinline__ float softplusf(float x) { return fmaxf(x, 0.0f) + log1pf(expf(-fabsf(x))); }

struct HeadArgs {
  const float *Wrk, *brk, *Wrs, *brs, *Wwk, *bwk, *Wws, *bws, *Wev, *bev,
              *Wwv, *bwv, *Wfg, *bfg, *Wag, *bag, *Wwg, *bwg, *Wrm, *brm;
};

// ---------------- K1: linear heads + activations ----------------
__global__ __launch_bounds__(256) void k1_heads(const float* __restrict__ xi, HeadArgs ha,
                                                float* __restrict__ iface) {
  __shared__ __align__(16) float xs[ID];
  __shared__ float raw[256];
  int b = blockIdx.x, t = threadIdx.x;
  for (int i = t; i < ID; i += 256) xs[i] = xi[b * ID + i];
  __syncthreads();
  const float* Ws[10] = {ha.Wrk, ha.Wrs, ha.Wwk, ha.Wws, ha.Wev, ha.Wwv, ha.Wfg, ha.Wag, ha.Wwg, ha.Wrm};
  const float* bs[10] = {ha.brk, ha.brs, ha.bwk, ha.bws, ha.bev, ha.bwv, ha.bfg, ha.bag, ha.bwg, ha.brm};
  const int off[11] = {0, 128, 132, 164, 165, 197, 229, 233, 234, 235, 247};
  float val = 0.0f;
  int h = -1, row = 0;
  if (t < 247) {
    for (int k = 0; k < 10; ++k)
      if (t >= off[k] && t < off[k + 1]) { h = k; row = t - off[k]; }
    const float4* w4 = (const float4*)(Ws[h] + row * ID);
    const float4* x4 = (const float4*)xs;
    float acc = 0.0f;
    for (int i = 0; i < ID / 4; ++i) {
      float4 w = w4[i], x = x4[i];
      acc += w.x * x.x + w.y * x.y + w.z * x.z + w.w * x.w;
    }
    val = acc + bs[h][row];
  }
  raw[t] = val;
  __syncthreads();
  if (t < 247) {
    float o;
    if (h == 0 || h == 2 || h == 5) o = tanhf(val);
    else if (h == 1 || h == 3) o = softplusf(val);
    else if (h == 9) {
      int g = (t - 235) / 3;
      float a0 = raw[235 + g * 3], a1 = raw[236 + g * 3], a2 = raw[237 + g * 3];
      float mx = fmaxf(a0, fmaxf(a1, a2));
      o = expf(val - mx) / (expf(a0 - mx) + expf(a1 - mx) + expf(a2 - mx));
    } else o = sigm(val);
    iface[b * 256 + t] = o;
  }
}

// ---------------- K2: usage/alloc/write-addressing/memory-write (R0 bitonic) ----------------
__global__ __launch_bounds__(512) void k2_write(const float* __restrict__ mem_in,
                                                const float* __restrict__ prec_in,
                                                const float* __restrict__ rw_in,
                                                const float* __restrict__ wwt_in,
                                                const float* __restrict__ usg_in,
                                                const float* __restrict__ iface,
                                                float* __restrict__ bw,
                                                float* __restrict__ out) {
  __shared__ __align__(16) float sif[256];
  __shared__ float sv[NN];
  __shared__ int si[NN];
  __shared__ float salloc[NN];
  __shared__ float sred[8];
  __shared__ float swt[8];
  int b = blockIdx.x, tid = threadIdx.x;
  int lane = tid & 63, wave = tid >> 6;

  // zero the bw accumulator for the atomic path (harmless in partial mode)
  for (int i = tid; i < RR * NN; i += 512) bw[(size_t)b * RR * NN + i] = 0.0f;

  if (tid < 256) sif[tid] = iface[b * 256 + tid];
  __syncthreads();

  // psi and usage update
  const float* rwb = rw_in + (size_t)b * RR * NN;
  float psi = 1.0f;
#pragma unroll
  for (int r = 0; r < RR; r++) psi *= 1.0f - sif[IF_FG + r] * rwb[r * NN + tid];
  float u = usg_in[b * NN + tid], wwt = wwt_in[b * NN + tid];
  u = (u + wwt - u * wwt) * psi;

  // ---- bitonic sort of (u, tid) ascending, in registers ----
  float v = u; int idx = tid;
  for (int k = 2; k <= NN; k <<= 1) {
    for (int j = k >> 1; j > 0; j >>= 1) {
      int p = tid ^ j;
      float pv; int pi;
      if (j >= 64) {
        sv[tid] = v; si[tid] = idx;
        __syncthreads();
        pv = sv[p]; pi = si[p];
        __syncthreads();
      } else {
        pv = __shfl_xor(v, j);
        pi = __shfl_xor(idx, j);
      }
      bool mineSmaller = (v < pv) || (v == pv && idx < pi);
      bool keepMin = (((tid & k) == 0) == (tid < p));
      bool take = keepMin ? !mineSmaller : mineSmaller;
      if (take) { v = pv; idx = pi; }
    }
  }

  // ---- exclusive product scan over sorted values ----
  float pr = v;
#pragma unroll
  for (int o = 1; o < 64; o <<= 1) {
    float q = __shfl_up(pr, o);
    if (lane >= o) pr *= q;
  }
  if (lane == 63) swt[wave] = pr;
  __syncthreads();
  float wp = 1.0f;
#pragma unroll
  for (int w = 0; w < 8; w++) if (w < wave) wp *= swt[w];
  float ep = __shfl_up(pr, 1);
  if (lane == 0) ep = 1.0f;
  float alloc_sorted = (1.0f - v) * (wp * ep);
  salloc[idx] = alloc_sorted;
  __syncthreads();
  float alloc = salloc[tid];

  // ---- write content addressing on OLD memory ----
  const float4* mrow = (const float4*)(mem_in + ((size_t)b * NN + tid) * WDIM);
  float4 mv[8];
  float dot = 0, nrm = 0, wkn = 0;
#pragma unroll
  for (int i = 0; i < 8; i++) {
    float4 m = mrow[i];
    mv[i] = m;
    const float4 kk = *(const float4*)&sif[IF_WK + 4 * i];
    dot += m.x * kk.x + m.y * kk.y + m.z * kk.z + m.w * kk.w;
    nrm += m.x * m.x + m.y * m.y + m.z * m.z + m.w * m.w;
    wkn += kk.x * kk.x + kk.y * kk.y + kk.z * kk.z + kk.w * kk.w;
  }
  float s = sif[IF_WS] * (dot / (sqrtf(nrm) * sqrtf(wkn) + EPSF));

  float m8 = s;
#pragma unroll
  for (int d = 32; d > 0; d >>= 1) m8 = fmaxf(m8, __shfl_down(m8, d));
  if (lane == 0) sred[wave] = m8;
  __syncthreads();
  float mx = sred[0];
#pragma unroll
  for (int w = 1; w < 8; w++) mx = fmaxf(mx, sred[w]);
  __syncthreads();
  float e = expf(s - mx);
  float sm = e;
#pragma unroll
  for (int d = 32; d > 0; d >>= 1) sm += __shfl_down(sm, d);
  if (lane == 0) sred[wave] = sm;
  __syncthreads();
  float esum = 0;
#pragma unroll
  for (int w = 0; w < 8; w++) esum += sred[w];
  __syncthreads();
  float wc = e / esum;

  float ww = sif[IF_WG] * (sif[IF_AG] * alloc + (1.0f - sif[IF_AG]) * wc);
  out[OFF_WW + b * NN + tid] = ww;
  out[OFF_USG + b * NN + tid] = u;

  float ws_ = ww;
#pragma unroll
  for (int d = 32; d > 0; d >>= 1) ws_ += __shfl_down(ws_, d);
  if (lane == 0) sred[wave] = ws_;
  __syncthreads();
  float wsum = 0;
#pragma unroll
  for (int w = 0; w < 8; w++) wsum += sred[w];
  out[OFF_PREC + b * NN + tid] = (1.0f - wsum) * prec_in[b * NN + tid] + ww;

  // memory erase + write
  float* mo = out + OFF_MEM + ((size_t)b * NN + tid) * WDIM;
#pragma unroll
  for (int i = 0; i < 8; i++) {
    float4 m = mv[i];
    float4 o;
    o.x = m.x * (1.0f - ww * sif[IF_EV + 4 * i + 0]) + ww * sif[IF_WV + 4 * i + 0];
    o.y = m.y * (1.0f - ww * sif[IF_EV + 4 * i + 1]) + ww * sif[IF_WV + 4 * i + 1];
    o.z = m.z * (1.0f - ww * sif[IF_EV + 4 * i + 2]) + ww * sif[IF_WV + 4 * i + 2];
    o.w = m.w * (1.0f - ww * sif[IF_EV + 4 * i + 3]) + ww * sif[IF_WV + 4 * i + 3];
    ((float4*)mo)[i] = o;
  }
}

// ---------------- K3: link update + fused fw/bw einsums ----------------
// R0 structure + ONE isolated change: 2-deep register prefetch (rows i+1 and i+2
// in flight) while keeping the register-cached ww/prec/rw columns. R1 bundled
// this with per-row LDS re-reads; this isolates the prefetch-depth variable.
template<int PARTIAL>
__global__ __launch_bounds__(256) void k3_link(const float* __restrict__ link_in,
                                               const float* __restrict__ prec_in,
                                               const float* __restrict__ rw_in,
                                               const float* __restrict__ ww_out,
                                               float* __restrict__ link_out,
                                               float* __restrict__ fw,
                                               float* __restrict__ bw) {
  __shared__ __align__(16) float sww[NN];
  __shared__ __align__(16) float sprec[NN];
  __shared__ __align__(16) float srw[RR * NN];
  __shared__ float sbw[RR * NN];
  int b = blockIdx.y, tile = blockIdx.x, tid = threadIdx.x;
  for (int i = tid; i < NN; i += 256) {
    sww[i] = ww_out[b * NN + i];
    sprec[i] = prec_in[b * NN + i];
  }
  for (int i = tid; i < RR * NN; i += 256) {
    srw[i] = rw_in[(size_t)b * RR * NN + i];
    sbw[i] = 0.0f;
  }
  __syncthreads();

  int wave = tid >> 6, lane = tid & 63;
  float4 cww[2], cpr[2], crw[RR][2];
#pragma unroll
  for (int h = 0; h < 2; h++) {
    cww[h] = ((const float4*)sww)[h * 64 + lane];
    cpr[h] = ((const float4*)sprec)[h * 64 + lane];
#pragma unroll
    for (int r = 0; r < RR; r++) crw[r][h] = ((const float4*)(srw + r * NN))[h * 64 + lane];
  }

  float bwa[RR][8];
#pragma unroll
  for (int r = 0; r < RR; r++)
#pragma unroll
    for (int j = 0; j < 8; j++) bwa[r][j] = 0.0f;

  const size_t lbase = (size_t)b * NN * NN;
  const float* lbp = link_in + lbase;
  int row0 = tile * 32 + wave;

  // 2-deep prefetch: buffer A holds rows row0+8k, buffer B holds rows row0+4+8k
  float4 na0 = ((const float4*)(lbp + (size_t)row0 * NN))[lane];
  float4 na1 = ((const float4*)(lbp + (size_t)row0 * NN))[64 + lane];
  float4 nb0 = ((const float4*)(lbp + (size_t)(row0 + 4) * NN))[lane];
  float4 nb1 = ((const float4*)(lbp + (size_t)(row0 + 4) * NN))[64 + lane];

  for (int i = 0; i < 8; i++) {
    int row = row0 + 4 * i;
    float4 cv[2];
    if ((i & 1) == 0) { cv[0] = na0; cv[1] = na1; } else { cv[0] = nb0; cv[1] = nb1; }
    if (i < 6) {
      const float4* Ln = (const float4*)(lbp + (size_t)(row + 8) * NN);
      if ((i & 1) == 0) { na0 = Ln[lane]; na1 = Ln[64 + lane]; }
      else              { nb0 = Ln[lane]; nb1 = Ln[64 + lane]; }
    }
    float wwr = sww[row];
    float rwr[RR] = {srw[row], srw[NN + row], srw[2 * NN + row], srw[3 * NN + row]};
    nt_float4* Lo = (nt_float4*)(link_out + lbase + (size_t)row * NN);
    float fp[RR] = {0, 0, 0, 0};
#pragma unroll
    for (int h = 0; h < 2; h++) {
      float4 lv = cv[h];
      float l[4] = {lv.x, lv.y, lv.z, lv.w};
      float wc[4] = {cww[h].x, cww[h].y, cww[h].z, cww[h].w};
      float pc[4] = {cpr[h].x, cpr[h].y, cpr[h].z, cpr[h].w};
      int c0 = h * 256 + 4 * lane;
#pragma unroll
      for (int j = 0; j < 4; j++) {
        float ln = (1.0f - wwr - wc[j]) * l[j] + wwr * pc[j];
        if (c0 + j == row) ln = 0.0f;
        l[j] = ln;
#pragma unroll
        for (int r = 0; r < RR; r++) bwa[r][h * 4 + j] += ln * rwr[r];
      }
#pragma unroll
      for (int r = 0; r < RR; r++) {
        float rc0 = (r == 0) ? crw[0][h].x : (r == 1) ? crw[1][h].x : (r == 2) ? crw[2][h].x : crw[3][h].x;
        float rc1 = (r == 0) ? crw[0][h].y : (r == 1) ? crw[1][h].y : (r == 2) ? crw[2][h].y : crw[3][h].y;
        float rc2 = (r == 0) ? crw[0][h].z : (r == 1) ? crw[1][h].z : (r == 2) ? crw[2][h].z : crw[3][h].z;
        float rc3 = (r == 0) ? crw[0][h].w : (r == 1) ? crw[1][h].w : (r == 2) ? crw[2][h].w : crw[3][h].w;
        fp[r] += l[0] * rc0 + l[1] * rc1 + l[2] * rc2 + l[3] * rc3;
      }
      nt_float4 ov = {l[0], l[1], l[2], l[3]};
      __builtin_nontemporal_store(ov, &Lo[h * 64 + lane]);   // link_out is never re-read: bypass caches
    }
#pragma unroll
    for (int d = 32; d > 0; d >>= 1) {
      fp[0] += __shfl_down(fp[0], d);
      fp[1] += __shfl_down(fp[1], d);
      fp[2] += __shfl_down(fp[2], d);
      fp[3] += __shfl_down(fp[3], d);
    }
    if (lane == 0) {
      float* fwb = fw + (size_t)b * RR * NN;
      fwb[0 * NN + row] = fp[0];
      fwb[1 * NN + row] = fp[1];
      fwb[2 * NN + row] = fp[2];
      fwb[3 * NN + row] = fp[3];
    }
  }

  // combine bw register partials across the 4 waves via LDS, then global merge
  for (int w = 0; w < 4; w++) {
    if (wave == w) {
#pragma unroll
      for (int r = 0; r < RR; r++)
#pragma unroll
        for (int h = 0; h < 2; h++)
#pragma unroll
          for (int j = 0; j < 4; j++)
            sbw[r * NN + h * 256 + 4 * lane + j] += bwa[r][h * 4 + j];
    }
    __syncthreads();
  }
  if (PARTIAL) {
    float* bp = bw + ((size_t)(b * NTILE + tile)) * RR * NN;
    for (int i = tid; i < RR * NN; i += 256) bp[i] = sbw[i];
  } else {
    float* bp = bw + (size_t)b * RR * NN;
    for (int i = tid; i < RR * NN; i += 256) atomicAdd(&bp[i], sbw[i]);
  }
}

// ---------------- K4: read addressing + read weights + read vectors ----------------
// grid: BB*RR blocks, one (batch, read-head) each (R0 structure).
template<int PARTIAL>
__global__ __launch_bounds__(512) void k4_read(const float* __restrict__ iface,
                                               const float* __restrict__ fw,
                                               const float* __restrict__ bw,
                                               float* __restrict__ out) {
  __shared__ __align__(16) float srk[WDIM];
  __shared__ float sred[8];
  __shared__ float srwn[NN];
  __shared__ float spart[16][WDIM];
  int b = blockIdx.x >> 2, r = blockIdx.x & 3;
  int tid = threadIdx.x, lane = tid & 63, wave = tid >> 6;
  const float* ifb = iface + b * 256;
  if (tid < WDIM) srk[tid] = ifb[IF_RK + r * WDIM + tid];
  __syncthreads();
  float rkn2 = 0;
#pragma unroll
  for (int w = 0; w < WDIM; w++) { float v = srk[w]; rkn2 += v * v; }
  float rkn = sqrtf(rkn2);

  const float* mem = out + OFF_MEM + (size_t)b * NN * WDIM;
  const float4* mrow = (const float4*)(mem + (size_t)tid * WDIM);
  float d = 0, nrm = 0;
#pragma unroll
  for (int i = 0; i < 8; i++) {
    float4 m = mrow[i];
    const float4 kk = *(const float4*)&srk[4 * i];
    nrm += m.x * m.x + m.y * m.y + m.z * m.z + m.w * m.w;
    d += m.x * kk.x + m.y * kk.y + m.z * kk.z + m.w * kk.w;
  }
  float s = ifb[IF_RS + r] * (d / (sqrtf(nrm) * rkn + EPSF));

  float m8 = s;
#pragma unroll
  for (int dd = 32; dd > 0; dd >>= 1) m8 = fmaxf(m8, __shfl_down(m8, dd));
  if (lane == 0) sred[wave] = m8;
  __syncthreads();
  float mx = sred[0];
#pragma unroll
  for (int w = 1; w < 8; w++) mx = fmaxf(mx, sred[w]);
  __syncthreads();
  float e = expf(s - mx);
  float sm = e;
#pragma unroll
  for (int dd = 32; dd > 0; dd >>= 1) sm += __shfl_down(sm, dd);
  if (lane == 0) sred[wave] = sm;
  __syncthreads();
  float esum = 0;
#pragma unroll
  for (int w = 0; w < 8; w++) esum += sred[w];
  float rc = e / esum;

  float bwv;
  if (PARTIAL) {
    const float* pp = bw + ((size_t)b * NTILE * RR + r) * NN + tid;
    float acc = 0.0f;
#pragma unroll
    for (int t = 0; t < NTILE; t++) acc += pp[(size_t)t * RR * NN];
    bwv = acc;
  } else {
    bwv = bw[((size_t)b * RR + r) * NN + tid];
  }
  float fwv = fw[((size_t)b * RR + r) * NN + tid];
  float m0 = ifb[IF_RM + 3 * r], m1 = ifb[IF_RM + 3 * r + 1], m2 = ifb[IF_RM + 3 * r + 2];
  float v = m0 * bwv + m1 * rc + m2 * fwv;
  srwn[tid] = v;
  out[OFF_RW + ((size_t)b * RR + r) * NN + tid] = v;
  __syncthreads();

  // rv[b,r,w] = sum_n srwn[n] * mem[n][w]
  int w = tid & 31, part = tid >> 5;     // 16 partitions of 32 rows
  float acc = 0;
  const float* mp = mem + (size_t)part * 32 * WDIM + w;
  const float* rp = srwn + part * 32;
#pragma unroll
  for (int n = 0; n < 32; n++) acc += rp[n] * mp[(size_t)n * WDIM];
  spart[part][w] = acc;
  __syncthreads();
  if (tid < WDIM) {
    float vv = 0;
#pragma unroll
    for (int p = 0; p < 16; p++) vv += spart[p][tid];
    out[OFF_RV + ((size_t)b * RR + r) * WDIM + tid] = vv;
  }
}

extern "C" void kernel_launch(void* const* d_in, const int* in_sizes, int n_in,
                              void* d_out, int out_size, void* d_ws, size_t ws_size,
                              hipStream_t stream) {
  const float* xi = (const float*)d_in[0];
  const float* mem = (const float*)d_in[1];
  const float* link = (const float*)d_in[2];
  const float* prec = (const float*)d_in[3];
  const float* rw = (const float*)d_in[4];
  const float* wwt = (const float*)d_in[5];
  const float* usg = (const float*)d_in[6];
  HeadArgs ha;
  ha.Wrk = (const float*)d_in[7];  ha.brk = (const float*)d_in[8];
  ha.Wrs = (const float*)d_in[9];  ha.brs = (const float*)d_in[10];
  ha.Wwk = (const float*)d_in[11]; ha.bwk = (const float*)d_in[12];
  ha.Wws = (const float*)d_in[13]; ha.bws = (const float*)d_in[14];
  ha.Wev = (const float*)d_in[15]; ha.bev = (const float*)d_in[16];
  ha.Wwv = (const float*)d_in[17]; ha.bwv = (const float*)d_in[18];
  ha.Wfg = (const float*)d_in[19]; ha.bfg = (const float*)d_in[20];
  ha.Wag = (const float*)d_in[21]; ha.bag = (const float*)d_in[22];
  ha.Wwg = (const float*)d_in[23]; ha.bwg = (const float*)d_in[24];
  ha.Wrm = (const float*)d_in[25]; ha.brm = (const float*)d_in[26];

  float* out = (float*)d_out;
  float* ws = (float*)d_ws;
  float* iface = ws + WS_IFACE;
  float* fwbuf = ws + WS_FW;
  float* bwbuf = ws + WS_BW;

  const size_t need_part_bytes = (WS_PART + WS_PART_FLOATS) * sizeof(float);
  const bool use_partial = ws_size >= need_part_bytes;

  k1_heads<<<BB, 256, 0, stream>>>(xi, ha, iface);
  k2_write<<<BB, 512, 0, stream>>>(mem, prec, rw, wwt, usg, iface, bwbuf, out);
  if (use_partial) {
    k3_link<1><<<dim3(NTILE, BB), 256, 0, stream>>>(link, prec, rw, out + OFF_WW, out + OFF_LINK, fwbuf, ws + WS_PART);
    k4_read<1><<<BB * RR, 512, 0, stream>>>(iface, fwbuf, ws + WS_PART, out);
  } else {
    k3_link<0><<<dim3(NTILE, BB), 256, 0, stream>>>(link, prec, rw, out + OFF_WW, out + OFF_LINK, fwbuf, bwbuf);
    k4_read<0><<<BB * RR, 512, 0, stream>>>(iface, fwbuf, bwbuf, out);
  }
}